// Round 13
// baseline (428.582 us; speedup 1.0000x reference)
//
#include <hip/hip_runtime.h>
#include <hip/hip_bf16.h>

#define N_NODES 10000
#define N_EDGES 80000
#define ETOT (N_EDGES + N_NODES)   // 90000
#define FD 128
#define D1 2048                    // H1*C1 = 8*256
#define D2 32
#define NEG 0.2f

typedef __hip_bfloat16 bf16;
typedef __attribute__((ext_vector_type(8))) short short8;
typedef __attribute__((ext_vector_type(4))) short short4v;
typedef __attribute__((ext_vector_type(4))) float f32x4;
typedef __attribute__((ext_vector_type(2))) float f32x2;

__device__ __forceinline__ bf16 f2b(float v){ return __float2bfloat16(v); }
__device__ __forceinline__ short f2bs(float v){ bf16 t=__float2bfloat16(v); return *(short*)&t; }
__device__ __forceinline__ float b2fs(short s){
    return __uint_as_float(((unsigned int)(unsigned short)s) << 16);
}

// ---------- deg count ----------
__global__ void k_deg(const int* __restrict__ ei, int* __restrict__ deg){
    int e = blockIdx.x*256 + threadIdx.x;
    if(e < N_EDGES) atomicAdd(&deg[ei[N_EDGES+e]], 1);
}

// ---------- CSR build (also zeroes cursor) ----------
__global__ void k_scan(const int* __restrict__ deg, int* __restrict__ row_start,
                       int* __restrict__ cursor){
    __shared__ int sdata[256];
    int tid = threadIdx.x;
    const int CH = 40;                            // 256*40 = 10240 >= N+1
    int base = tid*CH;
    int lsum = 0;
    for(int i=0;i<CH;i++){
        int v=base+i;
        if(v<N_NODES){ lsum += deg[v]+1; cursor[v]=0; }
    }
    sdata[tid]=lsum; __syncthreads();
    for(int off=1; off<256; off<<=1){
        int val = (tid>=off)? sdata[tid-off] : 0;
        __syncthreads();
        sdata[tid] += val;
        __syncthreads();
    }
    int run = (tid>0)? sdata[tid-1] : 0;
    for(int i=0;i<CH;i++){
        int v=base+i;
        if(v<=N_NODES){
            row_start[v]=run;
            if(v<N_NODES) run += deg[v]+1;
        }
    }
}

__global__ void k_fill(const int* __restrict__ ei, const int* __restrict__ row_start,
                       int* __restrict__ cursor, int* __restrict__ ecsr,
                       int* __restrict__ srcs, int* __restrict__ dsts){
    int e = blockIdx.x*256 + threadIdx.x;
    if(e >= ETOT) return;
    int src = (e < N_EDGES) ? ei[e]          : (e - N_EDGES);
    int dst = (e < N_EDGES) ? ei[N_EDGES+e]  : (e - N_EDGES);
    int p = atomicAdd(&cursor[dst], 1);
    int pos = row_start[dst]+p;
    ecsr[pos] = e;
    srcs[pos] = src;
    dsts[pos] = dst;
}

// ---------- self-loop attr: mean of incoming ea rows; 4 edges in flight ----------
__global__ void k_selfmean(const int* __restrict__ ecsr, const int* __restrict__ row_start,
                           const float* __restrict__ ea, float* __restrict__ self_attr){
    __shared__ float ssum[4][FD];
    __shared__ int scnt[4];
    int v = blockIdx.x, tid = threadIdx.x;        // 128 threads
    int eg = tid>>5, lane = tid&31;
    int start=row_start[v], end=row_start[v+1];
    float4 s={0,0,0,0}; int cnt=0;
    for(int i=start+eg;i<end;i+=4){
        int e=ecsr[i];
        if(e<N_EDGES){
            float4 vv = *(const float4*)(ea+(size_t)e*FD+lane*4);
            s.x+=vv.x; s.y+=vv.y; s.z+=vv.z; s.w+=vv.w; cnt++;
        }
    }
    *(float4*)&ssum[eg][lane*4] = s;
    if(lane==0) scnt[eg]=cnt;
    __syncthreads();
    float tot = ssum[0][tid]+ssum[1][tid]+ssum[2][tid]+ssum[3][tid];
    int c = scnt[0]+scnt[1]+scnt[2]+scnt[3];
    self_attr[(size_t)v*FD+tid] = tot / fmaxf((float)c, 1.f);
}

// ---------- merged weight pack: y=0..2 -> [128,2048] packs; y=3 -> W2 + W2e ----------
__global__ void k_packAll(const float* __restrict__ We1, const float* __restrict__ Wl1,
                          const float* __restrict__ Wr1, const float* __restrict__ Wl2,
                          const float* __restrict__ Wr2, const float* __restrict__ We2,
                          short* __restrict__ Wb1, short* __restrict__ Wbl1,
                          short* __restrict__ Wbr1, short* __restrict__ Wb2,
                          short* __restrict__ Wb2e){
    int y = blockIdx.y;
    int idx = blockIdx.x*256 + threadIdx.x;      // up to 262144
    if(y < 3){
        const float* W = (y==0)? We1 : (y==1)? Wl1 : Wr1;
        short* Wb      = (y==0)? Wb1 : (y==1)? Wbl1 : Wbr1;
        int k = idx >> 11, c = idx & 2047;
        int cb = c>>4, col = c&15, kc = k>>5, quad = (k>>3)&3, j = k&7;
        Wb[((size_t)(cb*4+kc)*64 + quad*16 + col)*8 + j] = f2bs(W[idx]);
    } else {
        if(idx < 131072){
            int k = idx >> 6, c = idx & 63;
            float v = (c < 32) ? Wl2[k*32 + c] : Wr2[k*32 + (c-32)];
            int cb = c>>4, col = c&15, kc = k>>5, quad = (k>>3)&3, j = k&7;
            Wb2[((size_t)(cb*64+kc)*64 + quad*16 + col)*8 + j] = f2bs(v);
        } else if(idx < 131072+4096){
            int t = idx - 131072;
            int k = t >> 5, c = t & 31;
            int cb = c>>4, col = c&15, kc = k>>5, quad = (k>>3)&3, j = k&7;
            Wb2e[((size_t)(cb*4+kc)*64 + quad*16 + col)*8 + j] = f2bs(We2[t]);
        }
    }
}

// ---------- layer-1 node GEMM via MFMA, 64 rows/block (both W via grid.y) ----------
__global__ __launch_bounds__(256) void k_gemm1m(const float* __restrict__ x,
        const short* __restrict__ Wbl, const float* __restrict__ bl, bf16* __restrict__ outl,
        const short* __restrict__ Wbr, const float* __restrict__ br, bf16* __restrict__ outr){
    const short* Wb   = (blockIdx.y==0)? Wbl : Wbr;
    const float* bias = (blockIdx.y==0)? bl  : br;
    bf16* outp        = (blockIdx.y==0)? outl: outr;
    __shared__ short a_lds[64*128];          // 16 KB
    __shared__ float tile[4][32][20];        // 10 KB
    int tid = threadIdx.x;
    int r0 = blockIdx.x*64;
    for(int q=tid; q<64*32; q+=256){
        int m=q>>5, kq=(q&31)*4;
        int gr=r0+m;
        float4 v4 = {0,0,0,0};
        if(gr<N_NODES) v4 = *(const float4*)(x+(size_t)gr*FD+kq);
        int kc=kq>>5, quad=(kq>>3)&3, j=kq&7;   // j in {0,4}
        short4v sv; sv[0]=f2bs(v4.x); sv[1]=f2bs(v4.y); sv[2]=f2bs(v4.z); sv[3]=f2bs(v4.w);
        *(short4v*)&a_lds[((kc*4+quad)*64+m)*8+j] = sv;
    }
    __syncthreads();
    int w=tid>>6, lane=tid&63, quad=lane>>4, col=lane&15;
    int arow=lane&31, half=lane>>5;
    short8 af[4][4];
    #pragma unroll
    for(int mg=0;mg<4;mg++)
        #pragma unroll
        for(int kc=0;kc<4;kc++)
            af[mg][kc] = *(const short8*)&a_lds[((kc*4+quad)*64+mg*16+col)*8];
    int orowA = r0 + arow;
    int orowB = r0 + 32 + arow;
    for(int cbl=0;cbl<32;cbl++){
        int cbg = w*32+cbl;
        f32x4 c0={0,0,0,0}, c1={0,0,0,0}, c2={0,0,0,0}, c3={0,0,0,0};
        #pragma unroll
        for(int kc=0;kc<4;kc++){
            short8 bfr = *(const short8*)(Wb + ((size_t)(cbg*4+kc)*64 + lane)*8);
            c0 = __builtin_amdgcn_mfma_f32_16x16x32_bf16(af[0][kc], bfr, c0, 0,0,0);
            c1 = __builtin_amdgcn_mfma_f32_16x16x32_bf16(af[1][kc], bfr, c1, 0,0,0);
            c2 = __builtin_amdgcn_mfma_f32_16x16x32_bf16(af[2][kc], bfr, c2, 0,0,0);
            c3 = __builtin_amdgcn_mfma_f32_16x16x32_bf16(af[3][kc], bfr, c3, 0,0,0);
        }
        int cg = cbg*16 + half*8;
        float4 b0 = *(const float4*)(bias+cg);
        float4 b1v = *(const float4*)(bias+cg+4);
        float bb[8]={b0.x,b0.y,b0.z,b0.w,b1v.x,b1v.y,b1v.z,b1v.w};
        // pass A: rows r0..r0+31
        #pragma unroll
        for(int rg=0;rg<4;rg++){
            tile[w][quad*4+rg][col]    = c0[rg];
            tile[w][16+quad*4+rg][col] = c1[rg];
        }
        {
            float4 t0 = *(float4*)&tile[w][arow][half*8];
            float4 t1 = *(float4*)&tile[w][arow][half*8+4];
            if(orowA < N_NODES){
                float tv[8]={t0.x,t0.y,t0.z,t0.w,t1.x,t1.y,t1.z,t1.w};
                short8 ov;
                #pragma unroll
                for(int j=0;j<8;j++) ov[j] = f2bs(tv[j]+bb[j]);
                *(short8*)(outp + (size_t)orowA*D1 + cg) = ov;
            }
        }
        // pass B: rows r0+32..r0+63
        #pragma unroll
        for(int rg=0;rg<4;rg++){
            tile[w][quad*4+rg][col]    = c2[rg];
            tile[w][16+quad*4+rg][col] = c3[rg];
        }
        {
            float4 t0 = *(float4*)&tile[w][arow][half*8];
            float4 t1 = *(float4*)&tile[w][arow][half*8+4];
            if(orowB < N_NODES){
                float tv[8]={t0.x,t0.y,t0.z,t0.w,t1.x,t1.y,t1.z,t1.w};
                short8 ov;
                #pragma unroll
                for(int j=0;j<8;j++) ov[j] = f2bs(tv[j]+bb[j]);
                *(short8*)(outp + (size_t)orowB*D1 + cg) = ov;
            }
        }
    }
}

// ---------- layer-1 edge logits (round-9 structure, f32x2-packed epilogue) ----------
__global__ __launch_bounds__(256) void k_logit1(const int* __restrict__ ecsr,
        const int* __restrict__ srcs, const int* __restrict__ dsts,
        const float* __restrict__ ea, const float* __restrict__ self_attr,
        const bf16* __restrict__ xl1, const bf16* __restrict__ xr1,
        const short* __restrict__ Wb, const short* __restrict__ Wb2e,
        const float* __restrict__ att1,
        float* __restrict__ logits1p, float* __restrict__ e2){
    __shared__ short a_lds[64*128];          // 16 KB, A-frag order (64 rows)
    __shared__ float tile[4][32][20];        // 10 KB
    __shared__ int ssrc[64], sdst[64], sed[64];
    int tid = threadIdx.x;
    int i0 = blockIdx.x*64;
    if(tid<64){
        int i=i0+tid; if(i>=ETOT) i=ETOT-1;
        sed[tid]=ecsr[i]; ssrc[tid]=srcs[i]; sdst[tid]=dsts[i];
    }
    __syncthreads();
    // stage: float4 reads, 8B LDS writes
    for(int q=tid; q<64*32; q+=256){
        int m=q>>5, kq=(q&31)*4;
        int e=sed[m];
        const float* sp = (e<N_EDGES)? (ea+(size_t)e*FD+kq) : (self_attr+(size_t)(e-N_EDGES)*FD+kq);
        float4 v4 = *(const float4*)sp;
        int kc=kq>>5, quad=(kq>>3)&3, j=kq&7;   // j in {0,4}
        short4v sv; sv[0]=f2bs(v4.x); sv[1]=f2bs(v4.y); sv[2]=f2bs(v4.z); sv[3]=f2bs(v4.w);
        *(short4v*)&a_lds[((kc*4+quad)*64+m)*8+j] = sv;
    }
    __syncthreads();
    int w=tid>>6, lane=tid&63, quad=lane>>4, col=lane&15;
    int arow=lane&31, half=lane>>5;
    short8 af[4][4];
    #pragma unroll
    for(int mg=0;mg<4;mg++)
        #pragma unroll
        for(int kc=0;kc<4;kc++)
            af[mg][kc] = *(const short8*)&a_lds[((kc*4+quad)*64+mg*16+col)*8];
    const bf16* xlpA = xl1 + (size_t)ssrc[arow]*D1;
    const bf16* xrpA = xr1 + (size_t)sdst[arow]*D1;
    const bf16* xlpB = xl1 + (size_t)ssrc[32+arow]*D1;
    const bf16* xrpB = xr1 + (size_t)sdst[32+arow]*D1;
    f32x2 accv[4] = {{0,0},{0,0},{0,0},{0,0}};   // [passB*2 + headparity]
    for(int cbl=0;cbl<32;cbl++){
        int cbg = w*32+cbl;
        f32x4 c0={0,0,0,0}, c1={0,0,0,0}, c2={0,0,0,0}, c3={0,0,0,0};
        #pragma unroll
        for(int kc=0;kc<4;kc++){
            short8 bfr = *(const short8*)(Wb + ((size_t)(cbg*4+kc)*64 + lane)*8);
            c0 = __builtin_amdgcn_mfma_f32_16x16x32_bf16(af[0][kc], bfr, c0, 0,0,0);
            c1 = __builtin_amdgcn_mfma_f32_16x16x32_bf16(af[1][kc], bfr, c1, 0,0,0);
            c2 = __builtin_amdgcn_mfma_f32_16x16x32_bf16(af[2][kc], bfr, c2, 0,0,0);
            c3 = __builtin_amdgcn_mfma_f32_16x16x32_bf16(af[3][kc], bfr, c3, 0,0,0);
        }
        int hs = cbl>>4;
        int cg = cbg*16 + half*8;
        float4 a0 = *(const float4*)(att1+cg);
        float4 a1 = *(const float4*)(att1+cg+4);
        f32x2 avp[4] = {{a0.x,a0.y},{a0.z,a0.w},{a1.x,a1.y},{a1.z,a1.w}};
        // pass A: edges i0+0..31 (mg0,mg1)
        #pragma unroll
        for(int rg=0;rg<4;rg++){
            tile[w][quad*4+rg][col]    = c0[rg];
            tile[w][16+quad*4+rg][col] = c1[rg];
        }
        {
            float4 t0 = *(float4*)&tile[w][arow][half*8];
            float4 t1 = *(float4*)&tile[w][arow][half*8+4];
            short8 xlv = *(const short8*)(xlpA + cg);
            short8 xrv = *(const short8*)(xrpA + cg);
            f32x2 tvp[4]={{t0.x,t0.y},{t0.z,t0.w},{t1.x,t1.y},{t1.z,t1.w}};
            f32x2 acc = accv[hs];
            #pragma unroll
            for(int p=0;p<4;p++){
                f32x2 xlf = {b2fs(xlv[2*p]), b2fs(xlv[2*p+1])};
                f32x2 xrf = {b2fs(xrv[2*p]), b2fs(xrv[2*p+1])};
                f32x2 m = tvp[p] + xlf + xrf;
                m = __builtin_elementwise_max(m, m*NEG);
                acc += avp[p]*m;
            }
            accv[hs] = acc;
        }
        // pass B: edges i0+32..63 (mg2,mg3)
        #pragma unroll
        for(int rg=0;rg<4;rg++){
            tile[w][quad*4+rg][col]    = c2[rg];
            tile[w][16+quad*4+rg][col] = c3[rg];
        }
        {
            float4 t0 = *(float4*)&tile[w][arow][half*8];
            float4 t1 = *(float4*)&tile[w][arow][half*8+4];
            short8 xlv = *(const short8*)(xlpB + cg);
            short8 xrv = *(const short8*)(xrpB + cg);
            f32x2 tvp[4]={{t0.x,t0.y},{t0.z,t0.w},{t1.x,t1.y},{t1.z,t1.w}};
            f32x2 acc = accv[2+hs];
            #pragma unroll
            for(int p=0;p<4;p++){
                f32x2 xlf = {b2fs(xlv[2*p]), b2fs(xlv[2*p+1])};
                f32x2 xrf = {b2fs(xrv[2*p]), b2fs(xrv[2*p+1])};
                f32x2 m = tvp[p] + xlf + xrf;
                m = __builtin_elementwise_max(m, m*NEG);
                acc += avp[p]*m;
            }
            accv[2+hs] = acc;
        }
    }
    // fused layer-2 edge projection (waves 0,1): cols [w*16,(w+1)*16)
    if(w<2){
        f32x4 c0={0,0,0,0}, c1={0,0,0,0}, c2={0,0,0,0}, c3={0,0,0,0};
        #pragma unroll
        for(int kc=0;kc<4;kc++){
            short8 bfr = *(const short8*)(Wb2e + ((size_t)(w*4+kc)*64 + lane)*8);
            c0 = __builtin_amdgcn_mfma_f32_16x16x32_bf16(af[0][kc], bfr, c0, 0,0,0);
            c1 = __builtin_amdgcn_mfma_f32_16x16x32_bf16(af[1][kc], bfr, c1, 0,0,0);
            c2 = __builtin_amdgcn_mfma_f32_16x16x32_bf16(af[2][kc], bfr, c2, 0,0,0);
            c3 = __builtin_amdgcn_mfma_f32_16x16x32_bf16(af[3][kc], bfr, c3, 0,0,0);
        }
        #pragma unroll
        for(int rg=0;rg<4;rg++){
            tile[w][quad*4+rg][col]    = c0[rg];
            tile[w][16+quad*4+rg][col] = c1[rg];
        }
        {
            int i=i0+arow;
            float4 t0 = *(float4*)&tile[w][arow][half*8];
            float4 t1 = *(float4*)&tile[w][arow][half*8+4];
            if(i<ETOT){
                *(float4*)(e2 + (size_t)i*32 + w*16 + half*8)     = t0;
                *(float4*)(e2 + (size_t)i*32 + w*16 + half*8 + 4) = t1;
            }
        }
        #pragma unroll
        for(int rg=0;rg<4;rg++){
            tile[w][quad*4+rg][col]    = c2[rg];
            tile[w][16+quad*4+rg][col] = c3[rg];
        }
        {
            int i=i0+32+arow;
            float4 t0 = *(float4*)&tile[w][arow][half*8];
            float4 t1 = *(float4*)&tile[w][arow][half*8+4];
            if(i<ETOT){
                *(float4*)(e2 + (size_t)i*32 + w*16 + half*8)     = t0;
                *(float4*)(e2 + (size_t)i*32 + w*16 + half*8 + 4) = t1;
            }
        }
    }
    float acch[4];
    #pragma unroll
    for(int r=0;r<4;r++){
        acch[r] = accv[r].x + accv[r].y;
        acch[r] += __shfl_xor(acch[r],32);
    }
    if(lane<32){
        int iA=i0+arow;
        if(iA<ETOT){
            logits1p[(size_t)iA*8 + w*2  ] = acch[0];
            logits1p[(size_t)iA*8 + w*2+1] = acch[1];
        }
        int iB=i0+32+arow;
        if(iB<ETOT){
            logits1p[(size_t)iB*8 + w*2  ] = acch[2];
            logits1p[(size_t)iB*8 + w*2+1] = acch[3];
        }
    }
}

// ---------- layer-1 per-dst softmax + aggregation + bias + relu -> h (bf16) ----------
__global__ void k_agg1(const int* __restrict__ srcs, const int* __restrict__ row_start,
                       const float* __restrict__ logits1p, const bf16* __restrict__ xl1,
                       const float* __restrict__ b1, bf16* __restrict__ hb){
    int tid=threadIdx.x, v=blockIdx.x;
    int start=row_start[v], end=row_start[v+1];
    int w=tid>>6, lane=tid&63;
    int hpar = lane>>5;                  // 0: head 2w, 1: head 2w+1
    int myc = w*512 + lane*8;
    float ds0=0.f, ds1=0.f;
    for(int i=start+lane;i<end;i+=64){
        float2 lg = *(const float2*)(logits1p + (size_t)i*8 + w*2);
        ds0 += __expf(lg.x);
        ds1 += __expf(lg.y);
    }
    #pragma unroll
    for(int off=32;off>=1;off>>=1){
        ds0 += __shfl_xor(ds0,off);
        ds1 += __shfl_xor(ds1,off);
    }
    float rden = 1.f/((hpar==0)? ds0 : ds1);
    float acc[8]={0,0,0,0,0,0,0,0};
    int i=start;
    for(; i+2<=end; i+=2){
        int s0 = srcs[i], s1 = srcs[i+1];
        float2 g0 = *(const float2*)(logits1p + (size_t)i*8 + w*2);
        float2 g1 = *(const float2*)(logits1p + (size_t)(i+1)*8 + w*2);
        float a0v = __expf((hpar==0)? g0.x : g0.y) * rden;
        float a1v = __expf((hpar==0)? g1.x : g1.y) * rden;
        short8 x0 = *(const short8*)(xl1 + (size_t)s0*D1 + myc);
        short8 x1 = *(const short8*)(xl1 + (size_t)s1*D1 + myc);
        #pragma unroll
        for(int j=0;j<8;j++) acc[j] += a0v*b2fs(x0[j]) + a1v*b2fs(x1[j]);
    }
    if(i<end){
        int s0 = srcs[i];
        float2 g0 = *(const float2*)(logits1p + (size_t)i*8 + w*2);
        float a0v = __expf((hpar==0)? g0.x : g0.y) * rden;
        short8 x0 = *(const short8*)(xl1 + (size_t)s0*D1 + myc);
        #pragma unroll
        for(int j=0;j<8;j++) acc[j] += a0v*b2fs(x0[j]);
    }
    float4 bb0=*(const float4*)(b1+myc), bb1=*(const float4*)(b1+myc+4);
    float bv[8]={bb0.x,bb0.y,bb0.z,bb0.w,bb1.x,bb1.y,bb1.z,bb1.w};
    short8 ov;
    #pragma unroll
    for(int j=0;j<8;j++) ov[j] = f2bs(fmaxf(acc[j]+bv[j],0.f));
    *(short8*)(hb + (size_t)v*D1 + myc) = ov;
}

// ---------- layer-2 node GEMM via MFMA: [N,2048]@[2048,64]+b ----------
__global__ __launch_bounds__(256) void k_gemm2(const bf16* __restrict__ hb,
        const short* __restrict__ Wb2, const float* __restrict__ bl2,
        const float* __restrict__ br2, float* __restrict__ xl2, float* __restrict__ xr2){
    __shared__ float cacc[4][16][64];
    int tid=threadIdx.x, w=tid>>6, lane=tid&63, quad=lane>>4, col=lane&15;
    int r0 = blockIdx.x*16;
    const bf16* hp = hb + (size_t)(r0+col)*D1 + quad*8;
    f32x4 acc[4] = {{0,0,0,0},{0,0,0,0},{0,0,0,0},{0,0,0,0}};
    for(int kc=w*16; kc<w*16+16; kc++){
        short8 af = *(const short8*)(hp + kc*32);
        #pragma unroll
        for(int cb=0;cb<4;cb++){
            short8 bfr = *(const short8*)(Wb2 + ((size_t)(cb*64+kc)*64 + lane)*8);
            acc[cb] = __builtin_amdgcn_mfma_f32_16x16x32_bf16(af, bfr, acc[cb], 0,0,0);
        }
    }
    #pragma unroll
    for(int cb=0;cb<4;cb++)
        #pragma unroll
        for(int rg=0;rg<4;rg++)
            cacc[w][quad*4+rg][cb*16+col] = acc[cb][rg];
    __syncthreads();
    #pragma unroll
    for(int i=0;i<4;i++){
        int idx = tid + 256*i;
        int r = idx>>6, c = idx&63;
        float s = cacc[0][r][c]+cacc[1][r][c]+cacc[2][r][c]+cacc[3][r][c];
        int rr = r0 + r;
        if(c<32) xl2[rr*32+c]      = s + bl2[c];
        else     xr2[rr*32+(c-32)] = s + br2[c-32];
    }
}

// ---------- fused layer-2 edge logits + softmax + aggregation -> out ----------
// 4 nodes/block, one wave per node (single pass).
__global__ void k_agg2f(const int* __restrict__ srcs, const int* __restrict__ row_start,
                        const float* __restrict__ e2, const float* __restrict__ xl2,
                        const float* __restrict__ xr2, const float* __restrict__ att2,
                        const float* __restrict__ b2v, float* __restrict__ out){
    int tid=threadIdx.x;
    int w=tid>>6, lane=tid&63;
    int v=blockIdx.x*4+w;
    int start=row_start[v], end=row_start[v+1];
    int le=lane>>5, c=lane&31;
    float xr2v = xr2[v*32+c];
    float attc = att2[c];
    float ds=0.f, acc=0.f;
    for(int i=start+le;i<end;i+=2){
        int src=srcs[i];
        float xlv = xl2[src*32+c];
        float m = e2[(size_t)i*32+c] + xlv + xr2v;
        m = fmaxf(m, NEG*m);
        float p = attc*m;
        #pragma unroll
        for(int off=16;off>=1;off>>=1) p += __shfl_down(p,off,32);
        p = __shfl(p, 0, 32);
        float ep = __expf(p);
        ds  += ep;
        acc += ep*xlv;
    }
    ds  += __shfl_xor(ds,32);
    acc += __shfl_xor(acc,32);
    if(lane<32) out[(size_t)v*D2+c] = fmaxf(acc/ds + b2v[c], 0.f);
}

extern "C" void kernel_launch(void* const* d_in, const int* in_sizes, int n_in,
                              void* d_out, int out_size, void* d_ws, size_t ws_size,
                              hipStream_t stream) {
    const float* x    = (const float*)d_in[0];
    const int*   ei   = (const int*)d_in[1];
    const float* ea   = (const float*)d_in[2];
    const float* Wl1  = (const float*)d_in[3];
    const float* bl1  = (const float*)d_in[4];
    const float* Wr1  = (const float*)d_in[5];
    const float* br1  = (const float*)d_in[6];
    const float* We1  = (const float*)d_in[7];
    const float* att1 = (const float*)d_in[8];
    const float* b1   = (const float*)d_in[9];
    const float* Wl2  = (const float*)d_in[10];
    const float* bl2  = (const float*)d_in[11];
    const float* Wr2  = (const float*)d_in[12];
    const float* br2  = (const float*)d_in[13];
    const float* We2  = (const float*)d_in[14];
    const float* att2 = (const float*)d_in[15];
    const float* b2v  = (const float*)d_in[16];
    float* out = (float*)d_out;

    char* ws = (char*)d_ws;
    size_t off = 0;
    auto alloc = [&](size_t bytes)->char* {
        char* p = ws + off;
        off += (bytes + 255) & ~(size_t)255;
        return p;
    };
    float* self_attr = (float*)alloc((size_t)N_NODES*FD*4);
    int*   deg       = (int*)  alloc((size_t)N_NODES*4);
    int*   cursor    = (int*)  alloc((size_t)N_NODES*4);
    int*   row_start = (int*)  alloc((size_t)(N_NODES+1)*4);
    int*   ecsr      = (int*)  alloc((size_t)ETOT*4);
    int*   srcs      = (int*)  alloc((size_t)ETOT*4);
    int*   dsts      = (int*)  alloc((size_t)ETOT*4);
    float* logits1p  = (float*)alloc((size_t)ETOT*8*4);
    float* e2        = (float*)alloc((size_t)ETOT*32*4);
    bf16*  xl1       = (bf16*) alloc((size_t)N_NODES*D1*2);
    bf16*  xr1       = (bf16*) alloc((size_t)N_NODES*D1*2);
    bf16*  hb        = (bf16*) alloc((size_t)N_NODES*D1*2);
    float* xl2       = (float*)alloc((size_t)N_NODES*D2*4);
    float* xr2       = (float*)alloc((size_t)N_NODES*D2*4);
    short* Wb1       = (short*)alloc((size_t)FD*D1*2);
    short* Wbl1      = (short*)alloc((size_t)FD*D1*2);
    short* Wbr1      = (short*)alloc((size_t)FD*D1*2);
    short* Wb2       = (short*)alloc((size_t)D1*64*2);
    short* Wb2e      = (short*)alloc((size_t)FD*D2*2);
    (void)ws_size; (void)in_sizes; (void)n_in; (void)out_size;

    hipMemsetAsync(deg, 0, (size_t)N_NODES*4, stream);

    k_deg<<<(N_EDGES+255)/256, 256, 0, stream>>>(ei, deg);
    k_scan<<<1, 256, 0, stream>>>(deg, row_start, cursor);
    k_fill<<<(ETOT+255)/256, 256, 0, stream>>>(ei, row_start, cursor, ecsr, srcs, dsts);
    k_selfmean<<<N_NODES, 128, 0, stream>>>(ecsr, row_start, ea, self_attr);
    dim3 gp(1024, 4);
    k_packAll<<<gp, 256, 0, stream>>>(We1, Wl1, Wr1, Wl2, Wr2, We2,
                                      Wb1, Wbl1, Wbr1, Wb2, Wb2e);

    dim3 g1((N_NODES+63)/64, 2);
    k_gemm1m<<<g1, 256, 0, stream>>>(x, Wbl1, bl1, xl1, Wbr1, br1, xr1);

    k_logit1<<<(ETOT+63)/64, 256, 0, stream>>>(ecsr, srcs, dsts, ea, self_attr,
                                               xl1, xr1, Wb1, Wb2e, att1, logits1p, e2);
    k_agg1<<<N_NODES, 256, 0, stream>>>(srcs, row_start, logits1p, xl1, b1, hb);

    k_gemm2<<<N_NODES/16, 256, 0, stream>>>(hb, Wb2, bl2, br2, xl2, xr2);
    k_agg2f<<<N_NODES/4, 256, 0, stream>>>(srcs, row_start, e2, xl2, xr2, att2, b2v, out);
}

// Round 14
// 413.897 us; speedup vs baseline: 1.0355x; 1.0355x over previous
//
#include <hip/hip_runtime.h>
#include <hip/hip_bf16.h>

#define N_NODES 10000
#define N_EDGES 80000
#define ETOT (N_EDGES + N_NODES)   // 90000
#define FD 128
#define D1 2048                    // H1*C1 = 8*256
#define D2 32
#define NEG 0.2f

typedef __hip_bfloat16 bf16;
typedef __attribute__((ext_vector_type(8))) short short8;
typedef __attribute__((ext_vector_type(4))) short short4v;
typedef __attribute__((ext_vector_type(4))) float f32x4;

__device__ __forceinline__ bf16 f2b(float v){ return __float2bfloat16(v); }
__device__ __forceinline__ short f2bs(float v){ bf16 t=__float2bfloat16(v); return *(short*)&t; }
__device__ __forceinline__ float b2fs(short s){
    return __uint_as_float(((unsigned int)(unsigned short)s) << 16);
}

// ---------- deg count ----------
__global__ void k_deg(const int* __restrict__ ei, int* __restrict__ deg){
    int e = blockIdx.x*256 + threadIdx.x;
    if(e < N_EDGES) atomicAdd(&deg[ei[N_EDGES+e]], 1);
}

// ---------- CSR build (also zeroes cursor) ----------
__global__ void k_scan(const int* __restrict__ deg, int* __restrict__ row_start,
                       int* __restrict__ cursor){
    __shared__ int sdata[256];
    int tid = threadIdx.x;
    const int CH = 40;                            // 256*40 = 10240 >= N+1
    int base = tid*CH;
    int lsum = 0;
    for(int i=0;i<CH;i++){
        int v=base+i;
        if(v<N_NODES){ lsum += deg[v]+1; cursor[v]=0; }
    }
    sdata[tid]=lsum; __syncthreads();
    for(int off=1; off<256; off<<=1){
        int val = (tid>=off)? sdata[tid-off] : 0;
        __syncthreads();
        sdata[tid] += val;
        __syncthreads();
    }
    int run = (tid>0)? sdata[tid-1] : 0;
    for(int i=0;i<CH;i++){
        int v=base+i;
        if(v<=N_NODES){
            row_start[v]=run;
            if(v<N_NODES) run += deg[v]+1;
        }
    }
}

__global__ void k_fill(const int* __restrict__ ei, const int* __restrict__ row_start,
                       int* __restrict__ cursor, int* __restrict__ ecsr,
                       int* __restrict__ srcs, int* __restrict__ dsts){
    int e = blockIdx.x*256 + threadIdx.x;
    if(e >= ETOT) return;
    int src = (e < N_EDGES) ? ei[e]          : (e - N_EDGES);
    int dst = (e < N_EDGES) ? ei[N_EDGES+e]  : (e - N_EDGES);
    int p = atomicAdd(&cursor[dst], 1);
    int pos = row_start[dst]+p;
    ecsr[pos] = e;
    srcs[pos] = src;
    dsts[pos] = dst;
}

// ---------- self-loop attr: mean of incoming ea rows; 4 edges in flight ----------
__global__ void k_selfmean(const int* __restrict__ ecsr, const int* __restrict__ row_start,
                           const float* __restrict__ ea, float* __restrict__ self_attr){
    __shared__ float ssum[4][FD];
    __shared__ int scnt[4];
    int v = blockIdx.x, tid = threadIdx.x;        // 128 threads
    int eg = tid>>5, lane = tid&31;
    int start=row_start[v], end=row_start[v+1];
    float4 s={0,0,0,0}; int cnt=0;
    for(int i=start+eg;i<end;i+=4){
        int e=ecsr[i];
        if(e<N_EDGES){
            float4 vv = *(const float4*)(ea+(size_t)e*FD+lane*4);
            s.x+=vv.x; s.y+=vv.y; s.z+=vv.z; s.w+=vv.w; cnt++;
        }
    }
    *(float4*)&ssum[eg][lane*4] = s;
    if(lane==0) scnt[eg]=cnt;
    __syncthreads();
    float tot = ssum[0][tid]+ssum[1][tid]+ssum[2][tid]+ssum[3][tid];
    int c = scnt[0]+scnt[1]+scnt[2]+scnt[3];
    self_attr[(size_t)v*FD+tid] = tot / fmaxf((float)c, 1.f);
}

// ---------- merged weight pack: y=0..2 -> [128,2048] packs; y=3 -> W2 + W2e ----------
__global__ void k_packAll(const float* __restrict__ We1, const float* __restrict__ Wl1,
                          const float* __restrict__ Wr1, const float* __restrict__ Wl2,
                          const float* __restrict__ Wr2, const float* __restrict__ We2,
                          short* __restrict__ Wb1, short* __restrict__ Wbl1,
                          short* __restrict__ Wbr1, short* __restrict__ Wb2,
                          short* __restrict__ Wb2e){
    int y = blockIdx.y;
    int idx = blockIdx.x*256 + threadIdx.x;      // up to 262144
    if(y < 3){
        const float* W = (y==0)? We1 : (y==1)? Wl1 : Wr1;
        short* Wb      = (y==0)? Wb1 : (y==1)? Wbl1 : Wbr1;
        int k = idx >> 11, c = idx & 2047;
        int cb = c>>4, col = c&15, kc = k>>5, quad = (k>>3)&3, j = k&7;
        Wb[((size_t)(cb*4+kc)*64 + quad*16 + col)*8 + j] = f2bs(W[idx]);
    } else {
        if(idx < 131072){
            int k = idx >> 6, c = idx & 63;
            float v = (c < 32) ? Wl2[k*32 + c] : Wr2[k*32 + (c-32)];
            int cb = c>>4, col = c&15, kc = k>>5, quad = (k>>3)&3, j = k&7;
            Wb2[((size_t)(cb*64+kc)*64 + quad*16 + col)*8 + j] = f2bs(v);
        } else if(idx < 131072+4096){
            int t = idx - 131072;
            int k = t >> 5, c = t & 31;
            int cb = c>>4, col = c&15, kc = k>>5, quad = (k>>3)&3, j = k&7;
            Wb2e[((size_t)(cb*4+kc)*64 + quad*16 + col)*8 + j] = f2bs(We2[t]);
        }
    }
}

// ---------- layer-1 node GEMM via MFMA, 64 rows/block (both W via grid.y) ----------
__global__ __launch_bounds__(256) void k_gemm1m(const float* __restrict__ x,
        const short* __restrict__ Wbl, const float* __restrict__ bl, bf16* __restrict__ outl,
        const short* __restrict__ Wbr, const float* __restrict__ br, bf16* __restrict__ outr){
    const short* Wb   = (blockIdx.y==0)? Wbl : Wbr;
    const float* bias = (blockIdx.y==0)? bl  : br;
    bf16* outp        = (blockIdx.y==0)? outl: outr;
    __shared__ short a_lds[64*128];          // 16 KB
    __shared__ float tile[4][32][20];        // 10 KB
    int tid = threadIdx.x;
    int r0 = blockIdx.x*64;
    for(int q=tid; q<64*32; q+=256){
        int m=q>>5, kq=(q&31)*4;
        int gr=r0+m;
        float4 v4 = {0,0,0,0};
        if(gr<N_NODES) v4 = *(const float4*)(x+(size_t)gr*FD+kq);
        int kc=kq>>5, quad=(kq>>3)&3, j=kq&7;   // j in {0,4}
        short4v sv; sv[0]=f2bs(v4.x); sv[1]=f2bs(v4.y); sv[2]=f2bs(v4.z); sv[3]=f2bs(v4.w);
        *(short4v*)&a_lds[((kc*4+quad)*64+m)*8+j] = sv;
    }
    __syncthreads();
    int w=tid>>6, lane=tid&63, quad=lane>>4, col=lane&15;
    int arow=lane&31, half=lane>>5;
    short8 af[4][4];
    #pragma unroll
    for(int mg=0;mg<4;mg++)
        #pragma unroll
        for(int kc=0;kc<4;kc++)
            af[mg][kc] = *(const short8*)&a_lds[((kc*4+quad)*64+mg*16+col)*8];
    int orowA = r0 + arow;
    int orowB = r0 + 32 + arow;
    for(int cbl=0;cbl<32;cbl++){
        int cbg = w*32+cbl;
        f32x4 c0={0,0,0,0}, c1={0,0,0,0}, c2={0,0,0,0}, c3={0,0,0,0};
        #pragma unroll
        for(int kc=0;kc<4;kc++){
            short8 bfr = *(const short8*)(Wb + ((size_t)(cbg*4+kc)*64 + lane)*8);
            c0 = __builtin_amdgcn_mfma_f32_16x16x32_bf16(af[0][kc], bfr, c0, 0,0,0);
            c1 = __builtin_amdgcn_mfma_f32_16x16x32_bf16(af[1][kc], bfr, c1, 0,0,0);
            c2 = __builtin_amdgcn_mfma_f32_16x16x32_bf16(af[2][kc], bfr, c2, 0,0,0);
            c3 = __builtin_amdgcn_mfma_f32_16x16x32_bf16(af[3][kc], bfr, c3, 0,0,0);
        }
        int cg = cbg*16 + half*8;
        float4 b0 = *(const float4*)(bias+cg);
        float4 b1v = *(const float4*)(bias+cg+4);
        float bb[8]={b0.x,b0.y,b0.z,b0.w,b1v.x,b1v.y,b1v.z,b1v.w};
        // pass A: rows r0..r0+31
        #pragma unroll
        for(int rg=0;rg<4;rg++){
            tile[w][quad*4+rg][col]    = c0[rg];
            tile[w][16+quad*4+rg][col] = c1[rg];
        }
        {
            float4 t0 = *(float4*)&tile[w][arow][half*8];
            float4 t1 = *(float4*)&tile[w][arow][half*8+4];
            if(orowA < N_NODES){
                float tv[8]={t0.x,t0.y,t0.z,t0.w,t1.x,t1.y,t1.z,t1.w};
                short8 ov;
                #pragma unroll
                for(int j=0;j<8;j++) ov[j] = f2bs(tv[j]+bb[j]);
                *(short8*)(outp + (size_t)orowA*D1 + cg) = ov;
            }
        }
        // pass B: rows r0+32..r0+63
        #pragma unroll
        for(int rg=0;rg<4;rg++){
            tile[w][quad*4+rg][col]    = c2[rg];
            tile[w][16+quad*4+rg][col] = c3[rg];
        }
        {
            float4 t0 = *(float4*)&tile[w][arow][half*8];
            float4 t1 = *(float4*)&tile[w][arow][half*8+4];
            if(orowB < N_NODES){
                float tv[8]={t0.x,t0.y,t0.z,t0.w,t1.x,t1.y,t1.z,t1.w};
                short8 ov;
                #pragma unroll
                for(int j=0;j<8;j++) ov[j] = f2bs(tv[j]+bb[j]);
                *(short8*)(outp + (size_t)orowB*D1 + cg) = ov;
            }
        }
    }
}

// ---------- layer-1 edge logits (round-12 proven: 132.5 us) + fused layer-2 eproj ----------
__global__ __launch_bounds__(256) void k_logit1(const int* __restrict__ ecsr,
        const int* __restrict__ srcs, const int* __restrict__ dsts,
        const float* __restrict__ ea, const float* __restrict__ self_attr,
        const bf16* __restrict__ xl1, const bf16* __restrict__ xr1,
        const short* __restrict__ Wb, const short* __restrict__ Wb2e,
        const float* __restrict__ att1,
        float* __restrict__ logits1p, float* __restrict__ e2){
    __shared__ short a_lds[64*128];          // 16 KB, A-frag order (64 rows)
    __shared__ float tile[4][32][20];        // 10 KB
    __shared__ int ssrc[64], sdst[64], sed[64];
    int tid = threadIdx.x;
    int i0 = blockIdx.x*64;
    if(tid<64){
        int i=i0+tid; if(i>=ETOT) i=ETOT-1;
        sed[tid]=ecsr[i]; ssrc[tid]=srcs[i]; sdst[tid]=dsts[i];
    }
    __syncthreads();
    // stage: float4 reads, 8B LDS writes
    for(int q=tid; q<64*32; q+=256){
        int m=q>>5, kq=(q&31)*4;
        int e=sed[m];
        const float* sp = (e<N_EDGES)? (ea+(size_t)e*FD+kq) : (self_attr+(size_t)(e-N_EDGES)*FD+kq);
        float4 v4 = *(const float4*)sp;
        int kc=kq>>5, quad=(kq>>3)&3, j=kq&7;   // j in {0,4}
        short4v sv; sv[0]=f2bs(v4.x); sv[1]=f2bs(v4.y); sv[2]=f2bs(v4.z); sv[3]=f2bs(v4.w);
        *(short4v*)&a_lds[((kc*4+quad)*64+m)*8+j] = sv;
    }
    __syncthreads();
    int w=tid>>6, lane=tid&63, quad=lane>>4, col=lane&15;
    int arow=lane&31, half=lane>>5;
    short8 af[4][4];
    #pragma unroll
    for(int mg=0;mg<4;mg++)
        #pragma unroll
        for(int kc=0;kc<4;kc++)
            af[mg][kc] = *(const short8*)&a_lds[((kc*4+quad)*64+mg*16+col)*8];
    const bf16* xlpA = xl1 + (size_t)ssrc[arow]*D1;
    const bf16* xrpA = xr1 + (size_t)sdst[arow]*D1;
    const bf16* xlpB = xl1 + (size_t)ssrc[32+arow]*D1;
    const bf16* xrpB = xr1 + (size_t)sdst[32+arow]*D1;
    float acch[4]={0.f,0.f,0.f,0.f};   // [passB*2 + headparity]
    for(int cbl=0;cbl<32;cbl++){
        int cbg = w*32+cbl;
        f32x4 c0={0,0,0,0}, c1={0,0,0,0}, c2={0,0,0,0}, c3={0,0,0,0};
        #pragma unroll
        for(int kc=0;kc<4;kc++){
            short8 bfr = *(const short8*)(Wb + ((size_t)(cbg*4+kc)*64 + lane)*8);
            c0 = __builtin_amdgcn_mfma_f32_16x16x32_bf16(af[0][kc], bfr, c0, 0,0,0);
            c1 = __builtin_amdgcn_mfma_f32_16x16x32_bf16(af[1][kc], bfr, c1, 0,0,0);
            c2 = __builtin_amdgcn_mfma_f32_16x16x32_bf16(af[2][kc], bfr, c2, 0,0,0);
            c3 = __builtin_amdgcn_mfma_f32_16x16x32_bf16(af[3][kc], bfr, c3, 0,0,0);
        }
        int hs = cbl>>4;
        int cg = cbg*16 + half*8;
        float4 a0 = *(const float4*)(att1+cg);
        float4 a1 = *(const float4*)(att1+cg+4);
        float av[8]={a0.x,a0.y,a0.z,a0.w,a1.x,a1.y,a1.z,a1.w};
        // pass A: edges i0+0..31 (mg0,mg1)
        #pragma unroll
        for(int rg=0;rg<4;rg++){
            tile[w][quad*4+rg][col]    = c0[rg];
            tile[w][16+quad*4+rg][col] = c1[rg];
        }
        {
            float4 t0 = *(float4*)&tile[w][arow][half*8];
            float4 t1 = *(float4*)&tile[w][arow][half*8+4];
            short8 xlv = *(const short8*)(xlpA + cg);
            short8 xrv = *(const short8*)(xrpA + cg);
            float tv[8]={t0.x,t0.y,t0.z,t0.w,t1.x,t1.y,t1.z,t1.w};
            float acc = acch[hs];
            #pragma unroll
            for(int j=0;j<8;j++){
                float m = tv[j] + b2fs(xlv[j]) + b2fs(xrv[j]);
                m = (m>0.f)? m : NEG*m;
                acc += av[j]*m;
            }
            acch[hs] = acc;
        }
        // pass B: edges i0+32..63 (mg2,mg3)
        #pragma unroll
        for(int rg=0;rg<4;rg++){
            tile[w][quad*4+rg][col]    = c2[rg];
            tile[w][16+quad*4+rg][col] = c3[rg];
        }
        {
            float4 t0 = *(float4*)&tile[w][arow][half*8];
            float4 t1 = *(float4*)&tile[w][arow][half*8+4];
            short8 xlv = *(const short8*)(xlpB + cg);
            short8 xrv = *(const short8*)(xrpB + cg);
            float tv[8]={t0.x,t0.y,t0.z,t0.w,t1.x,t1.y,t1.z,t1.w};
            float acc = acch[2+hs];
            #pragma unroll
            for(int j=0;j<8;j++){
                float m = tv[j] + b2fs(xlv[j]) + b2fs(xrv[j]);
                m = (m>0.f)? m : NEG*m;
                acc += av[j]*m;
            }
            acch[2+hs] = acc;
        }
    }
    // fused layer-2 edge projection (waves 0,1): cols [w*16,(w+1)*16)
    if(w<2){
        f32x4 c0={0,0,0,0}, c1={0,0,0,0}, c2={0,0,0,0}, c3={0,0,0,0};
        #pragma unroll
        for(int kc=0;kc<4;kc++){
            short8 bfr = *(const short8*)(Wb2e + ((size_t)(w*4+kc)*64 + lane)*8);
            c0 = __builtin_amdgcn_mfma_f32_16x16x32_bf16(af[0][kc], bfr, c0, 0,0,0);
            c1 = __builtin_amdgcn_mfma_f32_16x16x32_bf16(af[1][kc], bfr, c1, 0,0,0);
            c2 = __builtin_amdgcn_mfma_f32_16x16x32_bf16(af[2][kc], bfr, c2, 0,0,0);
            c3 = __builtin_amdgcn_mfma_f32_16x16x32_bf16(af[3][kc], bfr, c3, 0,0,0);
        }
        #pragma unroll
        for(int rg=0;rg<4;rg++){
            tile[w][quad*4+rg][col]    = c0[rg];
            tile[w][16+quad*4+rg][col] = c1[rg];
        }
        {
            int i=i0+arow;
            float4 t0 = *(float4*)&tile[w][arow][half*8];
            float4 t1 = *(float4*)&tile[w][arow][half*8+4];
            if(i<ETOT){
                *(float4*)(e2 + (size_t)i*32 + w*16 + half*8)     = t0;
                *(float4*)(e2 + (size_t)i*32 + w*16 + half*8 + 4) = t1;
            }
        }
        #pragma unroll
        for(int rg=0;rg<4;rg++){
            tile[w][quad*4+rg][col]    = c2[rg];
            tile[w][16+quad*4+rg][col] = c3[rg];
        }
        {
            int i=i0+32+arow;
            float4 t0 = *(float4*)&tile[w][arow][half*8];
            float4 t1 = *(float4*)&tile[w][arow][half*8+4];
            if(i<ETOT){
                *(float4*)(e2 + (size_t)i*32 + w*16 + half*8)     = t0;
                *(float4*)(e2 + (size_t)i*32 + w*16 + half*8 + 4) = t1;
            }
        }
    }
    #pragma unroll
    for(int r=0;r<4;r++) acch[r] += __shfl_xor(acch[r],32);
    if(lane<32){
        int iA=i0+arow;
        if(iA<ETOT){
            logits1p[(size_t)iA*8 + w*2  ] = acch[0];
            logits1p[(size_t)iA*8 + w*2+1] = acch[1];
        }
        int iB=i0+32+arow;
        if(iB<ETOT){
            logits1p[(size_t)iB*8 + w*2  ] = acch[2];
            logits1p[(size_t)iB*8 + w*2+1] = acch[3];
        }
    }
}

// ---------- layer-1 per-dst softmax + aggregation + bias + relu -> h (bf16) ----------
__global__ void k_agg1(const int* __restrict__ srcs, const int* __restrict__ row_start,
                       const float* __restrict__ logits1p, const bf16* __restrict__ xl1,
                       const float* __restrict__ b1, bf16* __restrict__ hb){
    int tid=threadIdx.x, v=blockIdx.x;
    int start=row_start[v], end=row_start[v+1];
    int w=tid>>6, lane=tid&63;
    int hpar = lane>>5;                  // 0: head 2w, 1: head 2w+1
    int myc = w*512 + lane*8;
    float ds0=0.f, ds1=0.f;
    for(int i=start+lane;i<end;i+=64){
        float2 lg = *(const float2*)(logits1p + (size_t)i*8 + w*2);
        ds0 += __expf(lg.x);
        ds1 += __expf(lg.y);
    }
    #pragma unroll
    for(int off=32;off>=1;off>>=1){
        ds0 += __shfl_xor(ds0,off);
        ds1 += __shfl_xor(ds1,off);
    }
    float rden = 1.f/((hpar==0)? ds0 : ds1);
    float acc[8]={0,0,0,0,0,0,0,0};
    int i=start;
    for(; i+2<=end; i+=2){
        int s0 = srcs[i], s1 = srcs[i+1];
        float2 g0 = *(const float2*)(logits1p + (size_t)i*8 + w*2);
        float2 g1 = *(const float2*)(logits1p + (size_t)(i+1)*8 + w*2);
        float a0v = __expf((hpar==0)? g0.x : g0.y) * rden;
        float a1v = __expf((hpar==0)? g1.x : g1.y) * rden;
        short8 x0 = *(const short8*)(xl1 + (size_t)s0*D1 + myc);
        short8 x1 = *(const short8*)(xl1 + (size_t)s1*D1 + myc);
        #pragma unroll
        for(int j=0;j<8;j++) acc[j] += a0v*b2fs(x0[j]) + a1v*b2fs(x1[j]);
    }
    if(i<end){
        int s0 = srcs[i];
        float2 g0 = *(const float2*)(logits1p + (size_t)i*8 + w*2);
        float a0v = __expf((hpar==0)? g0.x : g0.y) * rden;
        short8 x0 = *(const short8*)(xl1 + (size_t)s0*D1 + myc);
        #pragma unroll
        for(int j=0;j<8;j++) acc[j] += a0v*b2fs(x0[j]);
    }
    float4 bb0=*(const float4*)(b1+myc), bb1=*(const float4*)(b1+myc+4);
    float bv[8]={bb0.x,bb0.y,bb0.z,bb0.w,bb1.x,bb1.y,bb1.z,bb1.w};
    short8 ov;
    #pragma unroll
    for(int j=0;j<8;j++) ov[j] = f2bs(fmaxf(acc[j]+bv[j],0.f));
    *(short8*)(hb + (size_t)v*D1 + myc) = ov;
}

// ---------- layer-2 node GEMM via MFMA: [N,2048]@[2048,64]+b ----------
__global__ __launch_bounds__(256) void k_gemm2(const bf16* __restrict__ hb,
        const short* __restrict__ Wb2, const float* __restrict__ bl2,
        const float* __restrict__ br2, float* __restrict__ xl2, float* __restrict__ xr2){
    __shared__ float cacc[4][16][64];
    int tid=threadIdx.x, w=tid>>6, lane=tid&63, quad=lane>>4, col=lane&15;
    int r0 = blockIdx.x*16;
    const bf16* hp = hb + (size_t)(r0+col)*D1 + quad*8;
    f32x4 acc[4] = {{0,0,0,0},{0,0,0,0},{0,0,0,0},{0,0,0,0}};
    for(int kc=w*16; kc<w*16+16; kc++){
        short8 af = *(const short8*)(hp + kc*32);
        #pragma unroll
        for(int cb=0;cb<4;cb++){
            short8 bfr = *(const short8*)(Wb2 + ((size_t)(cb*64+kc)*64 + lane)*8);
            acc[cb] = __builtin_amdgcn_mfma_f32_16x16x32_bf16(af, bfr, acc[cb], 0,0,0);
        }
    }
    #pragma unroll
    for(int cb=0;cb<4;cb++)
        #pragma unroll
        for(int rg=0;rg<4;rg++)
            cacc[w][quad*4+rg][cb*16+col] = acc[cb][rg];
    __syncthreads();
    #pragma unroll
    for(int i=0;i<4;i++){
        int idx = tid + 256*i;
        int r = idx>>6, c = idx&63;
        float s = cacc[0][r][c]+cacc[1][r][c]+cacc[2][r][c]+cacc[3][r][c];
        int rr = r0 + r;
        if(c<32) xl2[rr*32+c]      = s + bl2[c];
        else     xr2[rr*32+(c-32)] = s + br2[c-32];
    }
}

// ---------- fused layer-2 edge logits + softmax + aggregation -> out ----------
// 4 nodes/block, one wave per node (single pass).
__global__ void k_agg2f(const int* __restrict__ srcs, const int* __restrict__ row_start,
                        const float* __restrict__ e2, const float* __restrict__ xl2,
                        const float* __restrict__ xr2, const float* __restrict__ att2,
                        const float* __restrict__ b2v, float* __restrict__ out){
    int tid=threadIdx.x;
    int w=tid>>6, lane=tid&63;
    int v=blockIdx.x*4+w;
    int start=row_start[v], end=row_start[v+1];
    int le=lane>>5, c=lane&31;
    float xr2v = xr2[v*32+c];
    float attc = att2[c];
    float ds=0.f, acc=0.f;
    for(int i=start+le;i<end;i+=2){
        int src=srcs[i];
        float xlv = xl2[src*32+c];
        float m = e2[(size_t)i*32+c] + xlv + xr2v;
        m = fmaxf(m, NEG*m);
        float p = attc*m;
        #pragma unroll
        for(int off=16;off>=1;off>>=1) p += __shfl_down(p,off,32);
        p = __shfl(p, 0, 32);
        float ep = __expf(p);
        ds  += ep;
        acc += ep*xlv;
    }
    ds  += __shfl_xor(ds,32);
    acc += __shfl_xor(acc,32);
    if(lane<32) out[(size_t)v*D2+c] = fmaxf(acc/ds + b2v[c], 0.f);
}

extern "C" void kernel_launch(void* const* d_in, const int* in_sizes, int n_in,
                              void* d_out, int out_size, void* d_ws, size_t ws_size,
                              hipStream_t stream) {
    const float* x    = (const float*)d_in[0];
    const int*   ei   = (const int*)d_in[1];
    const float* ea   = (const float*)d_in[2];
    const float* Wl1  = (const float*)d_in[3];
    const float* bl1  = (const float*)d_in[4];
    const float* Wr1  = (const float*)d_in[5];
    const float* br1  = (const float*)d_in[6];
    const float* We1  = (const float*)d_in[7];
    const float* att1 = (const float*)d_in[8];
    const float* b1   = (const float*)d_in[9];
    const float* Wl2  = (const float*)d_in[10];
    const float* bl2  = (const float*)d_in[11];
    const float* Wr2  = (const float*)d_in[12];
    const float* br2  = (const float*)d_in[13];
    const float* We2  = (const float*)d_in[14];
    const float* att2 = (const float*)d_in[15];
    const float* b2v  = (const float*)d_in[16];
    float* out = (float*)d_out;

    char* ws = (char*)d_ws;
    size_t off = 0;
    auto alloc = [&](size_t bytes)->char* {
        char* p = ws + off;
        off += (bytes + 255) & ~(size_t)255;
        return p;
    };
    float* self_attr = (float*)alloc((size_t)N_NODES*FD*4);
    int*   deg       = (int*)  alloc((size_t)N_NODES*4);
    int*   cursor    = (int*)  alloc((size_t)N_NODES*4);
    int*   row_start = (int*)  alloc((size_t)(N_NODES+1)*4);
    int*   ecsr      = (int*)  alloc((size_t)ETOT*4);
    int*   srcs      = (int*)  alloc((size_t)ETOT*4);
    int*   dsts      = (int*)  alloc((size_t)ETOT*4);
    float* logits1p  = (float*)alloc((size_t)ETOT*8*4);
    float* e2        = (float*)alloc((size_t)ETOT*32*4);
    bf16*  xl1       = (bf16*) alloc((size_t)N_NODES*D1*2);
    bf16*  xr1       = (bf16*) alloc((size_t)N_NODES*D1*2);
    bf16*  hb        = (bf16*) alloc((size_t)N_NODES*D1*2);
    float* xl2       = (float*)alloc((size_t)N_NODES*D2*4);
    float* xr2       = (float*)alloc((size_t)N_NODES*D2*4);
    short* Wb1       = (short*)alloc((size_t)FD*D1*2);
    short* Wbl1      = (short*)alloc((size_t)FD*D1*2);
    short* Wbr1      = (short*)alloc((size_t)FD*D1*2);
    short* Wb2       = (short*)alloc((size_t)D1*64*2);
    short* Wb2e      = (short*)alloc((size_t)FD*D2*2);
    (void)ws_size; (void)in_sizes; (void)n_in; (void)out_size;

    hipMemsetAsync(deg, 0, (size_t)N_NODES*4, stream);

    k_deg<<<(N_EDGES+255)/256, 256, 0, stream>>>(ei, deg);
    k_scan<<<1, 256, 0, stream>>>(deg, row_start, cursor);
    k_fill<<<(ETOT+255)/256, 256, 0, stream>>>(ei, row_start, cursor, ecsr, srcs, dsts);
    k_selfmean<<<N_NODES, 128, 0, stream>>>(ecsr, row_start, ea, self_attr);
    dim3 gp(1024, 4);
    k_packAll<<<gp, 256, 0, stream>>>(We1, Wl1, Wr1, Wl2, Wr2, We2,
                                      Wb1, Wbl1, Wbr1, Wb2, Wb2e);

    dim3 g1((N_NODES+63)/64, 2);
    k_gemm1m<<<g1, 256, 0, stream>>>(x, Wbl1, bl1, xl1, Wbr1, br1, xr1);

    k_logit1<<<(ETOT+63)/64, 256, 0, stream>>>(ecsr, srcs, dsts, ea, self_attr,
                                               xl1, xr1, Wb1, Wb2e, att1, logits1p, e2);
    k_agg1<<<N_NODES, 256, 0, stream>>>(srcs, row_start, logits1p, xl1, b1, hb);

    k_gemm2<<<N_NODES/16, 256, 0, stream>>>(hb, Wb2, bl2, br2, xl2, xr2);
    k_agg2f<<<N_NODES/4, 256, 0, stream>>>(srcs, row_start, e2, xl2, xr2, att2, b2v, out);
}